// Round 1
// baseline (644.608 us; speedup 1.0000x reference)
//
#include <hip/hip_runtime.h>
#include <hip/hip_bf16.h>

#define TILE 32
#define CH 64

// ---------------- QKV fused projection ----------------
// grid = ceil(N/TILE), block = 256. Thread t owns output column t.
__global__ __launch_bounds__(256) void qkv_kernel(
    const float* __restrict__ X, const float* __restrict__ Wq,
    const float* __restrict__ Wk, const float* __restrict__ Wv,
    float* __restrict__ Q, float* __restrict__ K, float* __restrict__ V, int N) {
  __shared__ float Xs[TILE][256];
  int t = threadIdx.x;
  int r0 = blockIdx.x * TILE;
  for (int r = 0; r < TILE; ++r) {
    int row = r0 + r;
    Xs[r][t] = (row < N) ? X[(size_t)row * 256 + t] : 0.f;
  }
  __syncthreads();

  const float* Ws[3] = {Wq, Wk, Wv};
  float* Os[3] = {Q, K, V};
  for (int m = 0; m < 3; ++m) {
    const float* W = Ws[m];
    float acc[TILE];
#pragma unroll
    for (int r = 0; r < TILE; ++r) acc[r] = 0.f;
    for (int d = 0; d < 256; d += 4) {
      float w0 = W[(d + 0) * 256 + t];
      float w1 = W[(d + 1) * 256 + t];
      float w2 = W[(d + 2) * 256 + t];
      float w3 = W[(d + 3) * 256 + t];
#pragma unroll
      for (int r = 0; r < TILE; ++r) {
        float4 x = *reinterpret_cast<const float4*>(&Xs[r][d]);
        acc[r] += x.x * w0 + x.y * w1 + x.z * w2 + x.w * w3;
      }
    }
    float* O = Os[m];
    for (int r = 0; r < TILE; ++r) {
      int row = r0 + r;
      if (row < N) O[(size_t)row * 256 + t] = acc[r];
    }
  }
}

// ---------------- CSR build ----------------
__global__ void hist_kernel(const int* __restrict__ src, int* __restrict__ counts, int E) {
  int e = blockIdx.x * blockDim.x + threadIdx.x;
  if (e < E) atomicAdd(&counts[src[e]], 1);
}

__global__ __launch_bounds__(256) void scan_kernel(
    const int* __restrict__ counts, int* __restrict__ offs, int* __restrict__ cursor, int N) {
  __shared__ int buf[256];
  __shared__ int carry;
  int t = threadIdx.x;
  if (t == 0) carry = 0;
  __syncthreads();
  for (int base = 0; base < N; base += 256) {
    int i = base + t;
    int v = (i < N) ? counts[i] : 0;
    buf[t] = v;
    __syncthreads();
    for (int off = 1; off < 256; off <<= 1) {
      int add = (t >= off) ? buf[t - off] : 0;
      __syncthreads();
      buf[t] += add;
      __syncthreads();
    }
    int incl = buf[t];
    int c = carry;
    int excl = c + incl - v;
    if (i < N) { offs[i] = excl; cursor[i] = excl; }
    __syncthreads();
    if (t == 255) carry = c + incl;
    __syncthreads();
  }
  if (t == 0) offs[N] = carry;
}

__global__ void scatter_kernel(const int* __restrict__ src, const int* __restrict__ tgt,
                               const float* __restrict__ ew, int* __restrict__ cursor,
                               int* __restrict__ tgt_s, float* __restrict__ w_s, int E) {
  int e = blockIdx.x * blockDim.x + threadIdx.x;
  if (e < E) {
    int pos = atomicAdd(&cursor[src[e]], 1);
    tgt_s[pos] = tgt[e];
    w_s[pos] = ew[e];
  }
}

// ---------------- per-node attention (online softmax, CSR) ----------------
// grid = N, block = 256. Thread t owns output dim t; head h = t>>5.
__global__ __launch_bounds__(256) void attn_kernel(
    const float* __restrict__ Q, const float* __restrict__ K, const float* __restrict__ V,
    const int* __restrict__ offs, const int* __restrict__ tgt_s, const float* __restrict__ w_s,
    const float* __restrict__ We, float* __restrict__ AGG, int N) {
  int i = blockIdx.x;
  int t = threadIdx.x;
  int h = t >> 5;
  int l = t & 31;
  const float scale = 0.17677669529663687f;  // 1/sqrt(32)
  float q = Q[(size_t)i * 256 + t];
  float we = We[h];

  __shared__ float s_s[CH][8];
  __shared__ float s_p[CH][8];
  __shared__ int s_tgt[CH];
  __shared__ float s_w[CH];

  float m = -1e30f, lsum = 0.f, acc = 0.f;
  int beg = offs[i], end = offs[i + 1];

  for (int base = beg; base < end; base += CH) {
    int cnt = min(CH, end - base);
    if (t < cnt) {
      s_tgt[t] = tgt_s[base + t];
      s_w[t] = w_s[base + t];
    }
    __syncthreads();
    // scores for this chunk
    for (int j = 0; j < cnt; ++j) {
      float partial = q * K[(size_t)s_tgt[j] * 256 + t];
#pragma unroll
      for (int off = 16; off; off >>= 1) partial += __shfl_xor(partial, off, 32);
      if (l == 0) s_s[j][h] = partial * scale + s_w[j] * we;
    }
    __syncthreads();
    // online softmax update
    float cmax = -1e30f;
    for (int j = 0; j < cnt; ++j) cmax = fmaxf(cmax, s_s[j][h]);
    float newm = fmaxf(m, cmax);
    float f = __expf(m - newm);
    acc *= f;
    float psum = 0.f;
    for (int j = 0; j < cnt; ++j) {
      float p = __expf(s_s[j][h] - newm);
      if (l == 0) s_p[j][h] = p;
      psum += p;
    }
    lsum = lsum * f + psum;
    m = newm;
    __syncthreads();
    // weighted V accumulation
    for (int j = 0; j < cnt; ++j) {
      acc += s_p[j][h] * V[(size_t)s_tgt[j] * 256 + t];
    }
    __syncthreads();
  }
  AGG[(size_t)i * 256 + t] = (lsum > 0.f) ? acc / lsum : 0.f;
}

// ---------------- output GEMM + residual + LayerNorm ----------------
__global__ __launch_bounds__(256) void out_kernel(
    const float* __restrict__ AGG, const float* __restrict__ Wo,
    const float* __restrict__ X, const float* __restrict__ g, const float* __restrict__ b,
    float* __restrict__ out, int N) {
  __shared__ float S[TILE][256];
  __shared__ float s_mu[TILE], s_rs[TILE];
  int t = threadIdx.x;
  int r0 = blockIdx.x * TILE;
  for (int r = 0; r < TILE; ++r) {
    int row = r0 + r;
    S[r][t] = (row < N) ? AGG[(size_t)row * 256 + t] : 0.f;
  }
  __syncthreads();
  float acc[TILE];
#pragma unroll
  for (int r = 0; r < TILE; ++r) acc[r] = 0.f;
  for (int d = 0; d < 256; d += 4) {
    float w0 = Wo[(d + 0) * 256 + t];
    float w1 = Wo[(d + 1) * 256 + t];
    float w2 = Wo[(d + 2) * 256 + t];
    float w3 = Wo[(d + 3) * 256 + t];
#pragma unroll
    for (int r = 0; r < TILE; ++r) {
      float4 x = *reinterpret_cast<const float4*>(&S[r][d]);
      acc[r] += x.x * w0 + x.y * w1 + x.z * w2 + x.w * w3;
    }
  }
  __syncthreads();
  // residual add, stash x into LDS for row stats
  for (int r = 0; r < TILE; ++r) {
    int row = r0 + r;
    S[r][t] = acc[r] + ((row < N) ? X[(size_t)row * 256 + t] : 0.f);
  }
  __syncthreads();
  int wid = t >> 6, lane = t & 63;
  for (int r = wid; r < TILE; r += 4) {
    float s = 0.f, ss = 0.f;
    for (int c = lane; c < 256; c += 64) {
      float v = S[r][c];
      s += v;
      ss += v * v;
    }
#pragma unroll
    for (int off = 32; off; off >>= 1) {
      s += __shfl_xor(s, off);
      ss += __shfl_xor(ss, off);
    }
    if (lane == 0) {
      float mu = s * (1.f / 256.f);
      float var = ss * (1.f / 256.f) - mu * mu;
      s_mu[r] = mu;
      s_rs[r] = rsqrtf(var + 1e-5f);
    }
  }
  __syncthreads();
  float gg = g[t], bb = b[t];
  for (int r = 0; r < TILE; ++r) {
    int row = r0 + r;
    if (row < N) out[(size_t)row * 256 + t] = (S[r][t] - s_mu[r]) * s_rs[r] * gg + bb;
  }
}

extern "C" void kernel_launch(void* const* d_in, const int* in_sizes, int n_in,
                              void* d_out, int out_size, void* d_ws, size_t ws_size,
                              hipStream_t stream) {
  const float* X  = (const float*)d_in[0];
  const int* eidx = (const int*)d_in[1];
  const float* ew = (const float*)d_in[2];
  const float* Wq = (const float*)d_in[3];
  const float* Wk = (const float*)d_in[4];
  const float* Wv = (const float*)d_in[5];
  const float* We = (const float*)d_in[6];
  const float* Wo = (const float*)d_in[7];
  const float* g  = (const float*)d_in[8];
  const float* b  = (const float*)d_in[9];
  int N = in_sizes[0] / 256;
  int E = in_sizes[1] / 2;
  const int* src = eidx;
  const int* tgt = eidx + E;
  float* out = (float*)d_out;

  char* w = (char*)d_ws;
  float* Q = (float*)w;      w += (size_t)N * 256 * 4;
  float* K = (float*)w;      w += (size_t)N * 256 * 4;
  float* V = (float*)w;      w += (size_t)N * 256 * 4;
  int* counts = (int*)w;     w += (size_t)N * 4;
  int* offs = (int*)w;       w += (size_t)(N + 1) * 4;
  int* cursor = (int*)w;     w += (size_t)N * 4;
  int* tgt_s = (int*)w;      w += (size_t)E * 4;
  float* w_s = (float*)w;    w += (size_t)E * 4;
  float* AGG = out;  // reuse d_out as aggregation buffer (overwritten by out_kernel)

  hipMemsetAsync(counts, 0, (size_t)N * 4, stream);
  qkv_kernel<<<(N + TILE - 1) / TILE, 256, 0, stream>>>(X, Wq, Wk, Wv, Q, K, V, N);
  hist_kernel<<<(E + 255) / 256, 256, 0, stream>>>(src, counts, E);
  scan_kernel<<<1, 256, 0, stream>>>(counts, offs, cursor, N);
  scatter_kernel<<<(E + 255) / 256, 256, 0, stream>>>(src, tgt, ew, cursor, tgt_s, w_s, E);
  attn_kernel<<<N, 256, 0, stream>>>(Q, K, V, offs, tgt_s, w_s, We, AGG, N);
  out_kernel<<<(N + TILE - 1) / TILE, 256, 0, stream>>>(AGG, Wo, X, g, b, out, N);
}

// Round 2
// 302.340 us; speedup vs baseline: 2.1321x; 2.1321x over previous
//
#include <hip/hip_runtime.h>
#include <hip/hip_bf16.h>

typedef __attribute__((ext_vector_type(8))) short short8;
typedef __attribute__((ext_vector_type(4))) float f32x4;

#define CH 64

__device__ __forceinline__ ushort f2b(float f) {
  __hip_bfloat16 h = __float2bfloat16(f);
  return *reinterpret_cast<ushort*>(&h);
}
__device__ __forceinline__ float b2f(ushort u) {
  return __uint_as_float(((unsigned)u) << 16);
}

// ---------------- convert X to bf16 ----------------
__global__ __launch_bounds__(256) void convert_x(const float* __restrict__ X,
                                                 ushort* __restrict__ Xb, int n) {
  int i = (blockIdx.x * 256 + threadIdx.x) * 8;
  if (i >= n) return;
  float4 x0 = *reinterpret_cast<const float4*>(X + i);
  float4 x1 = *reinterpret_cast<const float4*>(X + i + 4);
  short8 o;
  o[0] = (short)f2b(x0.x); o[1] = (short)f2b(x0.y);
  o[2] = (short)f2b(x0.z); o[3] = (short)f2b(x0.w);
  o[4] = (short)f2b(x1.x); o[5] = (short)f2b(x1.y);
  o[6] = (short)f2b(x1.z); o[7] = (short)f2b(x1.w);
  *reinterpret_cast<short8*>(Xb + i) = o;
}

// ---------------- convert + transpose weights ----------------
// Wt rows 0..255 = Wq^T, 256..511 = Wk^T, 512..767 = Wv^T, 768..1023 = Wo^T
__global__ __launch_bounds__(256) void convert_w(
    const float* __restrict__ Wq, const float* __restrict__ Wk,
    const float* __restrict__ Wv, const float* __restrict__ Wo,
    ushort* __restrict__ Wt) {
  __shared__ float L[32][33];
  int bx = blockIdx.x;       // 0..255
  int mat = bx >> 6;
  int tile = bx & 63;
  int tr = (tile >> 3) * 32;  // k-tile
  int tc = (tile & 7) * 32;   // col-tile
  const float* W = (mat == 0) ? Wq : (mat == 1) ? Wk : (mat == 2) ? Wv : Wo;
  int t = threadIdx.x;
  int c = t & 31, r8 = t >> 5;
#pragma unroll
  for (int rr = 0; rr < 4; ++rr) {
    int r = r8 + rr * 8;
    L[r][c] = W[(size_t)(tr + r) * 256 + tc + c];
  }
  __syncthreads();
#pragma unroll
  for (int rr = 0; rr < 4; ++rr) {
    int cc = r8 + rr * 8;
    Wt[(size_t)(mat * 256 + tc + cc) * 256 + tr + c] = f2b(L[c][cc]);
  }
}

// ---------------- QKV fused MFMA GEMM ----------------
// C[N x 768] = Xb[N x 256] @ Wt[768 x 256]^T ; grid (N/32, 3), block 256.
// wave w handles cols blockIdx.y*256 + w*64 .. +63; 32 rows per block.
__global__ __launch_bounds__(256) void gemm_qkv(
    const ushort* __restrict__ Xb, const ushort* __restrict__ Wt,
    ushort* __restrict__ QKVb, int N) {
  int lane = threadIdx.x & 63;
  int wid = threadIdx.x >> 6;
  int row0 = blockIdx.x * 32;
  int col0 = blockIdx.y * 256 + wid * 64;
  int lr = lane & 15;
  int kg = (lane >> 4) * 8;
  f32x4 acc[2][4] = {};
  const ushort* A0 = Xb + (size_t)(row0 + lr) * 256 + kg;
  const ushort* A1 = A0 + 16 * 256;
  const ushort* Bb = Wt + (size_t)(col0 + lr) * 256 + kg;
#pragma unroll
  for (int k0 = 0; k0 < 256; k0 += 32) {
    short8 a0 = *reinterpret_cast<const short8*>(A0 + k0);
    short8 a1 = *reinterpret_cast<const short8*>(A1 + k0);
#pragma unroll
    for (int fc = 0; fc < 4; ++fc) {
      short8 bf = *reinterpret_cast<const short8*>(Bb + (size_t)fc * 16 * 256 + k0);
      acc[0][fc] = __builtin_amdgcn_mfma_f32_16x16x32_bf16(a0, bf, acc[0][fc], 0, 0, 0);
      acc[1][fc] = __builtin_amdgcn_mfma_f32_16x16x32_bf16(a1, bf, acc[1][fc], 0, 0, 0);
    }
  }
  int orow = (lane >> 4) * 4;
#pragma unroll
  for (int fr = 0; fr < 2; ++fr)
#pragma unroll
    for (int fc = 0; fc < 4; ++fc)
#pragma unroll
      for (int r = 0; r < 4; ++r) {
        int row = row0 + fr * 16 + orow + r;
        int col = col0 + fc * 16 + lr;
        QKVb[(size_t)row * 768 + col] = f2b(acc[fr][fc][r]);
      }
}

// ---------------- CSR build ----------------
__global__ void hist_kernel(const int* __restrict__ src, int* __restrict__ counts, int E) {
  int e = blockIdx.x * blockDim.x + threadIdx.x;
  if (e < E) atomicAdd(&counts[src[e]], 1);
}

__global__ __launch_bounds__(1024) void scan_kernel(
    const int* __restrict__ counts, int* __restrict__ offs, int* __restrict__ cursor, int N) {
  __shared__ int wexc[16];
  __shared__ int s_total;
  __shared__ int carry_s;
  int t = threadIdx.x;
  int lane = t & 63, wv = t >> 6;
  __shared__ int wsum[16];
  if (t == 0) carry_s = 0;
  __syncthreads();
  for (int base = 0; base < N; base += 1024) {
    int i = base + t;
    int v = (i < N) ? counts[i] : 0;
    int x = v;
#pragma unroll
    for (int off = 1; off < 64; off <<= 1) {
      int y = __shfl_up(x, off);
      if (lane >= off) x += y;
    }
    if (lane == 63) wsum[wv] = x;
    __syncthreads();
    if (t < 64) {
      int s = (lane < 16) ? wsum[lane] : 0;
      int xs = s;
#pragma unroll
      for (int off = 1; off < 16; off <<= 1) {
        int y = __shfl_up(xs, off);
        if (lane >= off) xs += y;
      }
      if (lane < 16) wexc[lane] = xs - s;
      if (lane == 15) s_total = xs;
    }
    __syncthreads();
    int carry = carry_s;
    int excl = carry + wexc[wv] + (x - v);
    if (i < N) { offs[i] = excl; cursor[i] = excl; }
    __syncthreads();
    if (t == 0) carry_s += s_total;
    __syncthreads();
  }
  if (t == 0) offs[N] = carry_s;
}

__global__ void scatter_kernel(const int* __restrict__ src, const int* __restrict__ tgt,
                               const float* __restrict__ ew, int* __restrict__ cursor,
                               int* __restrict__ tgt_s, float* __restrict__ w_s, int E) {
  int e = blockIdx.x * blockDim.x + threadIdx.x;
  if (e < E) {
    int pos = atomicAdd(&cursor[src[e]], 1);
    tgt_s[pos] = tgt[e];
    w_s[pos] = ew[e];
  }
}

// ---------------- per-node attention (online softmax, CSR, bf16 QKV) ----------------
__global__ __launch_bounds__(256) void attn_kernel(
    const ushort* __restrict__ QKVb,
    const int* __restrict__ offs, const int* __restrict__ tgt_s, const float* __restrict__ w_s,
    const float* __restrict__ We, ushort* __restrict__ AGGb, int N) {
  int i = blockIdx.x;
  int t = threadIdx.x;
  int h = t >> 5;
  int l = t & 31;
  const float scale = 0.17677669529663687f;  // 1/sqrt(32)
  float q = b2f(QKVb[(size_t)i * 768 + t]);
  float we = We[h];

  __shared__ float s_s[CH][8];
  __shared__ float s_p[CH][8];
  __shared__ int s_tgt[CH];
  __shared__ float s_w[CH];

  float m = -1e30f, lsum = 0.f, acc = 0.f;
  int beg = offs[i], end = offs[i + 1];

  for (int base = beg; base < end; base += CH) {
    int cnt = min(CH, end - base);
    if (t < cnt) {
      s_tgt[t] = tgt_s[base + t];
      s_w[t] = w_s[base + t];
    }
    __syncthreads();
    for (int j = 0; j < cnt; ++j) {
      float partial = q * b2f(QKVb[(size_t)s_tgt[j] * 768 + 256 + t]);
#pragma unroll
      for (int off = 16; off; off >>= 1) partial += __shfl_xor(partial, off, 32);
      if (l == 0) s_s[j][h] = partial * scale + s_w[j] * we;
    }
    __syncthreads();
    float cmax = -1e30f;
    for (int j = 0; j < cnt; ++j) cmax = fmaxf(cmax, s_s[j][h]);
    float newm = fmaxf(m, cmax);
    float f = __expf(m - newm);
    acc *= f;
    float psum = 0.f;
    for (int j = 0; j < cnt; ++j) {
      float p = __expf(s_s[j][h] - newm);
      if (l == 0) s_p[j][h] = p;
      psum += p;
    }
    lsum = lsum * f + psum;
    m = newm;
    __syncthreads();
    for (int j = 0; j < cnt; ++j) {
      acc += s_p[j][h] * b2f(QKVb[(size_t)s_tgt[j] * 768 + 512 + t]);
    }
    __syncthreads();
  }
  AGGb[(size_t)i * 256 + t] = f2b((lsum > 0.f) ? acc / lsum : 0.f);
}

// ---------------- output MFMA GEMM + residual + LayerNorm ----------------
// grid = N/32, block 256. wave w: cols w*64..w*64+63 of a 32x256 tile.
__global__ __launch_bounds__(256) void out_mfma(
    const ushort* __restrict__ AGGb, const ushort* __restrict__ Wot,
    const float* __restrict__ X, const float* __restrict__ g, const float* __restrict__ bb,
    float* __restrict__ out, int N) {
  __shared__ float S[32][264];
  __shared__ float s_mu[32], s_rs[32];
  int t = threadIdx.x;
  int lane = t & 63, wid = t >> 6;
  int row0 = blockIdx.x * 32;
  int col0 = wid * 64;
  int lr = lane & 15, kg = (lane >> 4) * 8;
  f32x4 acc[2][4] = {};
  const ushort* A0 = AGGb + (size_t)(row0 + lr) * 256 + kg;
  const ushort* A1 = A0 + 16 * 256;
  const ushort* Bb = Wot + (size_t)(col0 + lr) * 256 + kg;
#pragma unroll
  for (int k0 = 0; k0 < 256; k0 += 32) {
    short8 a0 = *reinterpret_cast<const short8*>(A0 + k0);
    short8 a1 = *reinterpret_cast<const short8*>(A1 + k0);
#pragma unroll
    for (int fc = 0; fc < 4; ++fc) {
      short8 bf = *reinterpret_cast<const short8*>(Bb + (size_t)fc * 16 * 256 + k0);
      acc[0][fc] = __builtin_amdgcn_mfma_f32_16x16x32_bf16(a0, bf, acc[0][fc], 0, 0, 0);
      acc[1][fc] = __builtin_amdgcn_mfma_f32_16x16x32_bf16(a1, bf, acc[1][fc], 0, 0, 0);
    }
  }
  int orow = (lane >> 4) * 4;
#pragma unroll
  for (int fr = 0; fr < 2; ++fr)
#pragma unroll
    for (int fc = 0; fc < 4; ++fc)
#pragma unroll
      for (int r = 0; r < 4; ++r) {
        int row = fr * 16 + orow + r;
        int col = col0 + fc * 16 + lr;
        S[row][col] = acc[fr][fc][r] + X[(size_t)(row0 + row) * 256 + col];
      }
  __syncthreads();
  for (int r = wid; r < 32; r += 4) {
    float s = 0.f, ss = 0.f;
    for (int c = lane; c < 256; c += 64) {
      float v = S[r][c];
      s += v;
      ss += v * v;
    }
#pragma unroll
    for (int off = 32; off; off >>= 1) {
      s += __shfl_xor(s, off);
      ss += __shfl_xor(ss, off);
    }
    if (lane == 0) {
      float mu = s * (1.f / 256.f);
      float var = ss * (1.f / 256.f) - mu * mu;
      s_mu[r] = mu;
      s_rs[r] = rsqrtf(var + 1e-5f);
    }
  }
  __syncthreads();
  float gg = g[t], bbv = bb[t];
  for (int r = 0; r < 32; ++r) {
    out[(size_t)(row0 + r) * 256 + t] = (S[r][t] - s_mu[r]) * s_rs[r] * gg + bbv;
  }
}

extern "C" void kernel_launch(void* const* d_in, const int* in_sizes, int n_in,
                              void* d_out, int out_size, void* d_ws, size_t ws_size,
                              hipStream_t stream) {
  const float* X  = (const float*)d_in[0];
  const int* eidx = (const int*)d_in[1];
  const float* ew = (const float*)d_in[2];
  const float* Wq = (const float*)d_in[3];
  const float* Wk = (const float*)d_in[4];
  const float* Wv = (const float*)d_in[5];
  const float* We = (const float*)d_in[6];
  const float* Wo = (const float*)d_in[7];
  const float* g  = (const float*)d_in[8];
  const float* b  = (const float*)d_in[9];
  int N = in_sizes[0] / 256;
  int E = in_sizes[1] / 2;
  const int* src = eidx;
  const int* tgt = eidx + E;
  float* out = (float*)d_out;

  char* w = (char*)d_ws;
  ushort* Xb   = (ushort*)w;  w += (size_t)N * 256 * 2;
  ushort* Wt   = (ushort*)w;  w += (size_t)1024 * 256 * 2;
  ushort* QKVb = (ushort*)w;  w += (size_t)N * 768 * 2;
  ushort* AGGb = (ushort*)w;  w += (size_t)N * 256 * 2;
  int* counts  = (int*)w;     w += (size_t)N * 4;
  int* offs    = (int*)w;     w += (size_t)(N + 1) * 4;
  int* cursor  = (int*)w;     w += (size_t)N * 4;
  int* tgt_s   = (int*)w;     w += (size_t)E * 4;
  float* w_s   = (float*)w;   w += (size_t)E * 4;
  const ushort* Wot = Wt + (size_t)768 * 256;

  hipMemsetAsync(counts, 0, (size_t)N * 4, stream);
  convert_x<<<(N * 256 + 2047) / 2048, 256, 0, stream>>>(X, Xb, N * 256);
  convert_w<<<256, 256, 0, stream>>>(Wq, Wk, Wv, Wo, Wt);
  gemm_qkv<<<dim3(N / 32, 3), 256, 0, stream>>>(Xb, Wt, QKVb, N);
  hist_kernel<<<(E + 255) / 256, 256, 0, stream>>>(src, counts, E);
  scan_kernel<<<1, 1024, 0, stream>>>(counts, offs, cursor, N);
  scatter_kernel<<<(E + 255) / 256, 256, 0, stream>>>(src, tgt, ew, cursor, tgt_s, w_s, E);
  attn_kernel<<<N, 256, 0, stream>>>(QKVb, offs, tgt_s, w_s, We, AGGb, N);
  out_mfma<<<N / 32, 256, 0, stream>>>(AGGb, Wot, X, g, b, out, N);
}

// Round 3
// 205.522 us; speedup vs baseline: 3.1364x; 1.4711x over previous
//
#include <hip/hip_runtime.h>
#include <hip/hip_bf16.h>

typedef __attribute__((ext_vector_type(8))) short short8;
typedef __attribute__((ext_vector_type(4))) short short4_t;
typedef __attribute__((ext_vector_type(4))) float f32x4;

#define CH 64

__device__ __forceinline__ ushort f2b(float f) {
  __hip_bfloat16 h = __float2bfloat16(f);
  return *reinterpret_cast<ushort*>(&h);
}
__device__ __forceinline__ float b2f(ushort u) {
  return __uint_as_float(((unsigned)u) << 16);
}
// wave-local LDS sync: drain this wave's DS ops; no block barrier (waves independent)
__device__ __forceinline__ void wave_lds_sync() {
  asm volatile("s_waitcnt lgkmcnt(0)" ::: "memory");
  __builtin_amdgcn_wave_barrier();
}

// ---------------- convert X to bf16 ----------------
__global__ __launch_bounds__(256) void convert_x(const float* __restrict__ X,
                                                 ushort* __restrict__ Xb, int n) {
  int i = (blockIdx.x * 256 + threadIdx.x) * 8;
  if (i >= n) return;
  float4 x0 = *reinterpret_cast<const float4*>(X + i);
  float4 x1 = *reinterpret_cast<const float4*>(X + i + 4);
  short8 o;
  o[0] = (short)f2b(x0.x); o[1] = (short)f2b(x0.y);
  o[2] = (short)f2b(x0.z); o[3] = (short)f2b(x0.w);
  o[4] = (short)f2b(x1.x); o[5] = (short)f2b(x1.y);
  o[6] = (short)f2b(x1.z); o[7] = (short)f2b(x1.w);
  *reinterpret_cast<short8*>(Xb + i) = o;
}

// ---------------- convert + transpose weights ----------------
__global__ __launch_bounds__(256) void convert_w(
    const float* __restrict__ Wq, const float* __restrict__ Wk,
    const float* __restrict__ Wv, const float* __restrict__ Wo,
    ushort* __restrict__ Wt) {
  __shared__ float L[32][33];
  int bx = blockIdx.x;
  int mat = bx >> 6;
  int tile = bx & 63;
  int tr = (tile >> 3) * 32;
  int tc = (tile & 7) * 32;
  const float* W = (mat == 0) ? Wq : (mat == 1) ? Wk : (mat == 2) ? Wv : Wo;
  int t = threadIdx.x;
  int c = t & 31, r8 = t >> 5;
#pragma unroll
  for (int rr = 0; rr < 4; ++rr) {
    int r = r8 + rr * 8;
    L[r][c] = W[(size_t)(tr + r) * 256 + tc + c];
  }
  __syncthreads();
#pragma unroll
  for (int rr = 0; rr < 4; ++rr) {
    int cc = r8 + rr * 8;
    Wt[(size_t)(mat * 256 + tc + cc) * 256 + tr + c] = f2b(L[c][cc]);
  }
}

// ---------------- QKV fused MFMA GEMM ----------------
__global__ __launch_bounds__(256) void gemm_qkv(
    const ushort* __restrict__ Xb, const ushort* __restrict__ Wt,
    ushort* __restrict__ QKVb, int N) {
  int lane = threadIdx.x & 63;
  int wid = threadIdx.x >> 6;
  int row0 = blockIdx.x * 32;
  int col0 = blockIdx.y * 256 + wid * 64;
  int lr = lane & 15;
  int kg = (lane >> 4) * 8;
  f32x4 acc[2][4] = {};
  const ushort* A0 = Xb + (size_t)(row0 + lr) * 256 + kg;
  const ushort* A1 = A0 + 16 * 256;
  const ushort* Bb = Wt + (size_t)(col0 + lr) * 256 + kg;
#pragma unroll
  for (int k0 = 0; k0 < 256; k0 += 32) {
    short8 a0 = *reinterpret_cast<const short8*>(A0 + k0);
    short8 a1 = *reinterpret_cast<const short8*>(A1 + k0);
#pragma unroll
    for (int fc = 0; fc < 4; ++fc) {
      short8 bf = *reinterpret_cast<const short8*>(Bb + (size_t)fc * 16 * 256 + k0);
      acc[0][fc] = __builtin_amdgcn_mfma_f32_16x16x32_bf16(a0, bf, acc[0][fc], 0, 0, 0);
      acc[1][fc] = __builtin_amdgcn_mfma_f32_16x16x32_bf16(a1, bf, acc[1][fc], 0, 0, 0);
    }
  }
  int orow = (lane >> 4) * 4;
#pragma unroll
  for (int fr = 0; fr < 2; ++fr)
#pragma unroll
    for (int fc = 0; fc < 4; ++fc)
#pragma unroll
      for (int r = 0; r < 4; ++r) {
        int row = row0 + fr * 16 + orow + r;
        int col = col0 + fc * 16 + lr;
        QKVb[(size_t)row * 768 + col] = f2b(acc[fr][fc][r]);
      }
}

// ---------------- CSR build ----------------
__global__ void hist_kernel(const int* __restrict__ src, int* __restrict__ counts, int E) {
  int e = blockIdx.x * blockDim.x + threadIdx.x;
  if (e < E) atomicAdd(&counts[src[e]], 1);
}

__global__ __launch_bounds__(1024) void scan_kernel(
    const int* __restrict__ counts, int* __restrict__ offs, int* __restrict__ cursor, int N) {
  __shared__ int wexc[16];
  __shared__ int s_total;
  __shared__ int carry_s;
  int t = threadIdx.x;
  int lane = t & 63, wv = t >> 6;
  __shared__ int wsum[16];
  if (t == 0) carry_s = 0;
  __syncthreads();
  for (int base = 0; base < N; base += 1024) {
    int i = base + t;
    int v = (i < N) ? counts[i] : 0;
    int x = v;
#pragma unroll
    for (int off = 1; off < 64; off <<= 1) {
      int y = __shfl_up(x, off);
      if (lane >= off) x += y;
    }
    if (lane == 63) wsum[wv] = x;
    __syncthreads();
    if (t < 64) {
      int s = (lane < 16) ? wsum[lane] : 0;
      int xs = s;
#pragma unroll
      for (int off = 1; off < 16; off <<= 1) {
        int y = __shfl_up(xs, off);
        if (lane >= off) xs += y;
      }
      if (lane < 16) wexc[lane] = xs - s;
      if (lane == 15) s_total = xs;
    }
    __syncthreads();
    int carry = carry_s;
    int excl = carry + wexc[wv] + (x - v);
    if (i < N) { offs[i] = excl; cursor[i] = excl; }
    __syncthreads();
    if (t == 0) carry_s += s_total;
    __syncthreads();
  }
  if (t == 0) offs[N] = carry_s;
}

__global__ void scatter_kernel(const int* __restrict__ src, const int* __restrict__ tgt,
                               const float* __restrict__ ew, int* __restrict__ cursor,
                               int* __restrict__ tgt_s, float* __restrict__ w_s, int E) {
  int e = blockIdx.x * blockDim.x + threadIdx.x;
  if (e < E) {
    int pos = atomicAdd(&cursor[src[e]], 1);
    tgt_s[pos] = tgt[e];
    w_s[pos] = ew[e];
  }
}

// ---------------- per-node attention: one WAVE per node ----------------
// grid ceil(N/4) x 256 threads (4 waves). Wave w owns node blockIdx.x*4+w.
// Phase 1: lane (e8=l>>3, h=l&7): full 32-dim head dot in registers.
// Phase 3: lane owns output dims l*4..l*4+3 (head l>>3).
// No __syncthreads; wave-private LDS + wave_lds_sync.
__global__ __launch_bounds__(256) void attn_kernel(
    const ushort* __restrict__ QKVb,
    const int* __restrict__ offs, const int* __restrict__ tgt_s, const float* __restrict__ w_s,
    const float* __restrict__ We, ushort* __restrict__ AGGb, int N) {
  __shared__ float s_p[4][CH][8];
  __shared__ int s_tgt[4][CH];
  __shared__ float s_w[4][CH];
  int t = threadIdx.x;
  int w = t >> 6;
  int l = t & 63;
  int i = blockIdx.x * 4 + w;
  if (i >= N) return;
  int e8 = l >> 3;
  int h = l & 7;
  int hacc = l >> 3;  // head for accumulation phase
  const float scale = 0.17677669529663687f;  // 1/sqrt(32)
  float we = We[h];

  // preload q fragment (dims h*32..h*32+31) as bf16 regs
  const short8* qr = reinterpret_cast<const short8*>(QKVb + (size_t)i * 768 + h * 32);
  short8 qv[4];
#pragma unroll
  for (int d = 0; d < 4; ++d) qv[d] = qr[d];

  float m = -1e30f, lsum = 0.f;
  float acc0 = 0.f, acc1 = 0.f, acc2 = 0.f, acc3 = 0.f;
  int beg = offs[i], end = offs[i + 1];

  for (int base = beg; base < end; base += CH) {
    int cnt = min(CH, end - base);
    if (l < cnt) {
      s_tgt[w][l] = tgt_s[base + l];
      s_w[w][l] = w_s[base + l];
    }
    wave_lds_sync();
    // ---- phase 1: scores, 8 edges x 8 heads per iteration ----
    float s_local[8];
    float cmax = -1e30f;
#pragma unroll
    for (int it = 0; it < 8; ++it) {
      int j = it * 8 + e8;
      float s = -1e30f;
      if (j < cnt) {
        const short8* kr = reinterpret_cast<const short8*>(
            QKVb + (size_t)s_tgt[w][j] * 768 + 256 + h * 32);
        float dot = 0.f;
#pragma unroll
        for (int d = 0; d < 4; ++d) {
          short8 kv = kr[d];
#pragma unroll
          for (int x = 0; x < 8; ++x)
            dot += b2f((ushort)qv[d][x]) * b2f((ushort)kv[x]);
        }
        s = dot * scale + s_w[w][j] * we;
      }
      s_local[it] = s;
      cmax = fmaxf(cmax, s);
    }
    // per-head max over e8 lanes (stride-8 groups): 3 shuffles per chunk
    cmax = fmaxf(cmax, __shfl_xor(cmax, 8));
    cmax = fmaxf(cmax, __shfl_xor(cmax, 16));
    cmax = fmaxf(cmax, __shfl_xor(cmax, 32));
    float newm = fmaxf(m, cmax);
    float f = __expf(m - newm);
    float psum = 0.f;
#pragma unroll
    for (int it = 0; it < 8; ++it) {
      int j = it * 8 + e8;
      if (j < cnt) {
        float p = __expf(s_local[it] - newm);
        s_p[w][j][h] = p;
        psum += p;
      }
    }
    psum += __shfl_xor(psum, 8);
    psum += __shfl_xor(psum, 16);
    psum += __shfl_xor(psum, 32);
    lsum = lsum * f + psum;
    m = newm;
    // rescale accumulator (factor for this lane's output head)
    float f_acc = __shfl(f, hacc);
    acc0 *= f_acc; acc1 *= f_acc; acc2 *= f_acc; acc3 *= f_acc;
    wave_lds_sync();
    // ---- phase 3: V aggregation, 512B/wave coalesced per edge ----
    for (int j = 0; j < cnt; ++j) {
      float p = s_p[w][j][hacc];
      short4_t vv = *reinterpret_cast<const short4_t*>(
          QKVb + (size_t)s_tgt[w][j] * 768 + 512 + l * 4);
      acc0 += p * b2f((ushort)vv[0]);
      acc1 += p * b2f((ushort)vv[1]);
      acc2 += p * b2f((ushort)vv[2]);
      acc3 += p * b2f((ushort)vv[3]);
    }
    wave_lds_sync();  // before next chunk overwrites staging
  }
  float lsum_acc = __shfl(lsum, hacc);
  float rinv = (lsum_acc > 0.f) ? 1.f / lsum_acc : 0.f;
  short4_t o;
  o[0] = (short)f2b(acc0 * rinv);
  o[1] = (short)f2b(acc1 * rinv);
  o[2] = (short)f2b(acc2 * rinv);
  o[3] = (short)f2b(acc3 * rinv);
  *reinterpret_cast<short4_t*>(AGGb + (size_t)i * 256 + l * 4) = o;
}

// ---------------- output MFMA GEMM + residual + LayerNorm ----------------
__global__ __launch_bounds__(256) void out_mfma(
    const ushort* __restrict__ AGGb, const ushort* __restrict__ Wot,
    const float* __restrict__ X, const float* __restrict__ g, const float* __restrict__ bb,
    float* __restrict__ out, int N) {
  __shared__ float S[32][264];
  __shared__ float s_mu[32], s_rs[32];
  int t = threadIdx.x;
  int lane = t & 63, wid = t >> 6;
  int row0 = blockIdx.x * 32;
  int col0 = wid * 64;
  int lr = lane & 15, kg = (lane >> 4) * 8;
  f32x4 acc[2][4] = {};
  const ushort* A0 = AGGb + (size_t)(row0 + lr) * 256 + kg;
  const ushort* A1 = A0 + 16 * 256;
  const ushort* Bb = Wot + (size_t)(col0 + lr) * 256 + kg;
#pragma unroll
  for (int k0 = 0; k0 < 256; k0 += 32) {
    short8 a0 = *reinterpret_cast<const short8*>(A0 + k0);
    short8 a1 = *reinterpret_cast<const short8*>(A1 + k0);
#pragma unroll
    for (int fc = 0; fc < 4; ++fc) {
      short8 bf = *reinterpret_cast<const short8*>(Bb + (size_t)fc * 16 * 256 + k0);
      acc[0][fc] = __builtin_amdgcn_mfma_f32_16x16x32_bf16(a0, bf, acc[0][fc], 0, 0, 0);
      acc[1][fc] = __builtin_amdgcn_mfma_f32_16x16x32_bf16(a1, bf, acc[1][fc], 0, 0, 0);
    }
  }
  int orow = (lane >> 4) * 4;
#pragma unroll
  for (int fr = 0; fr < 2; ++fr)
#pragma unroll
    for (int fc = 0; fc < 4; ++fc)
#pragma unroll
      for (int r = 0; r < 4; ++r) {
        int row = fr * 16 + orow + r;
        int col = col0 + fc * 16 + lr;
        S[row][col] = acc[fr][fc][r] + X[(size_t)(row0 + row) * 256 + col];
      }
  __syncthreads();
  for (int r = wid; r < 32; r += 4) {
    float s = 0.f, ss = 0.f;
    for (int c = lane; c < 256; c += 64) {
      float v = S[r][c];
      s += v;
      ss += v * v;
    }
#pragma unroll
    for (int off = 32; off; off >>= 1) {
      s += __shfl_xor(s, off);
      ss += __shfl_xor(ss, off);
    }
    if (lane == 0) {
      float mu = s * (1.f / 256.f);
      float var = ss * (1.f / 256.f) - mu * mu;
      s_mu[r] = mu;
      s_rs[r] = rsqrtf(var + 1e-5f);
    }
  }
  __syncthreads();
  float gg = g[t], bbv = bb[t];
  for (int r = 0; r < 32; ++r) {
    out[(size_t)(row0 + r) * 256 + t] = (S[r][t] - s_mu[r]) * s_rs[r] * gg + bbv;
  }
}

extern "C" void kernel_launch(void* const* d_in, const int* in_sizes, int n_in,
                              void* d_out, int out_size, void* d_ws, size_t ws_size,
                              hipStream_t stream) {
  const float* X  = (const float*)d_in[0];
  const int* eidx = (const int*)d_in[1];
  const float* ew = (const float*)d_in[2];
  const float* Wq = (const float*)d_in[3];
  const float* Wk = (const float*)d_in[4];
  const float* Wv = (const float*)d_in[5];
  const float* We = (const float*)d_in[6];
  const float* Wo = (const float*)d_in[7];
  const float* g  = (const float*)d_in[8];
  const float* b  = (const float*)d_in[9];
  int N = in_sizes[0] / 256;
  int E = in_sizes[1] / 2;
  const int* src = eidx;
  const int* tgt = eidx + E;
  float* out = (float*)d_out;

  char* w = (char*)d_ws;
  ushort* Xb   = (ushort*)w;  w += (size_t)N * 256 * 2;
  ushort* Wt   = (ushort*)w;  w += (size_t)1024 * 256 * 2;
  ushort* QKVb = (ushort*)w;  w += (size_t)N * 768 * 2;
  ushort* AGGb = (ushort*)w;  w += (size_t)N * 256 * 2;
  int* counts  = (int*)w;     w += (size_t)N * 4;
  int* offs    = (int*)w;     w += (size_t)(N + 1) * 4;
  int* cursor  = (int*)w;     w += (size_t)N * 4;
  int* tgt_s   = (int*)w;     w += (size_t)E * 4;
  float* w_s   = (float*)w;   w += (size_t)E * 4;
  const ushort* Wot = Wt + (size_t)768 * 256;

  hipMemsetAsync(counts, 0, (size_t)N * 4, stream);
  convert_x<<<(N * 256 + 2047) / 2048, 256, 0, stream>>>(X, Xb, N * 256);
  convert_w<<<256, 256, 0, stream>>>(Wq, Wk, Wv, Wo, Wt);
  gemm_qkv<<<dim3(N / 32, 3), 256, 0, stream>>>(Xb, Wt, QKVb, N);
  hist_kernel<<<(E + 255) / 256, 256, 0, stream>>>(src, counts, E);
  scan_kernel<<<1, 1024, 0, stream>>>(counts, offs, cursor, N);
  scatter_kernel<<<(E + 255) / 256, 256, 0, stream>>>(src, tgt, ew, cursor, tgt_s, w_s, E);
  attn_kernel<<<(N + 3) / 4, 256, 0, stream>>>(QKVb, offs, tgt_s, w_s, We, AGGb, N);
  out_mfma<<<N / 32, 256, 0, stream>>>(AGGb, Wot, X, g, b, out, N);
}

// Round 4
// 197.482 us; speedup vs baseline: 3.2641x; 1.0407x over previous
//
#include <hip/hip_runtime.h>
#include <hip/hip_bf16.h>

typedef __attribute__((ext_vector_type(8))) short short8;
typedef __attribute__((ext_vector_type(4))) short short4_t;
typedef __attribute__((ext_vector_type(4))) float f32x4;

#define CH 64

__device__ __forceinline__ ushort f2b(float f) {
  __hip_bfloat16 h = __float2bfloat16(f);
  return *reinterpret_cast<ushort*>(&h);
}
__device__ __forceinline__ float b2f(ushort u) {
  return __uint_as_float(((unsigned)u) << 16);
}
// wave-local LDS sync: drain this wave's DS ops; no block barrier (waves independent)
__device__ __forceinline__ void wave_lds_sync() {
  asm volatile("s_waitcnt lgkmcnt(0)" ::: "memory");
  __builtin_amdgcn_wave_barrier();
}

// ---------------- convert X to bf16 ----------------
__global__ __launch_bounds__(256) void convert_x(const float* __restrict__ X,
                                                 ushort* __restrict__ Xb, int n) {
  int i = (blockIdx.x * 256 + threadIdx.x) * 8;
  if (i >= n) return;
  float4 x0 = *reinterpret_cast<const float4*>(X + i);
  float4 x1 = *reinterpret_cast<const float4*>(X + i + 4);
  short8 o;
  o[0] = (short)f2b(x0.x); o[1] = (short)f2b(x0.y);
  o[2] = (short)f2b(x0.z); o[3] = (short)f2b(x0.w);
  o[4] = (short)f2b(x1.x); o[5] = (short)f2b(x1.y);
  o[6] = (short)f2b(x1.z); o[7] = (short)f2b(x1.w);
  *reinterpret_cast<short8*>(Xb + i) = o;
}

// ---------------- convert + transpose weights ----------------
__global__ __launch_bounds__(256) void convert_w(
    const float* __restrict__ Wq, const float* __restrict__ Wk,
    const float* __restrict__ Wv, const float* __restrict__ Wo,
    ushort* __restrict__ Wt) {
  __shared__ float L[32][33];
  int bx = blockIdx.x;
  int mat = bx >> 6;
  int tile = bx & 63;
  int tr = (tile >> 3) * 32;
  int tc = (tile & 7) * 32;
  const float* W = (mat == 0) ? Wq : (mat == 1) ? Wk : (mat == 2) ? Wv : Wo;
  int t = threadIdx.x;
  int c = t & 31, r8 = t >> 5;
#pragma unroll
  for (int rr = 0; rr < 4; ++rr) {
    int r = r8 + rr * 8;
    L[r][c] = W[(size_t)(tr + r) * 256 + tc + c];
  }
  __syncthreads();
#pragma unroll
  for (int rr = 0; rr < 4; ++rr) {
    int cc = r8 + rr * 8;
    Wt[(size_t)(mat * 256 + tc + cc) * 256 + tr + c] = f2b(L[c][cc]);
  }
}

// ---------------- QKV fused MFMA GEMM ----------------
__global__ __launch_bounds__(256) void gemm_qkv(
    const ushort* __restrict__ Xb, const ushort* __restrict__ Wt,
    ushort* __restrict__ QKVb, int N) {
  int lane = threadIdx.x & 63;
  int wid = threadIdx.x >> 6;
  int row0 = blockIdx.x * 32;
  int col0 = blockIdx.y * 256 + wid * 64;
  int lr = lane & 15;
  int kg = (lane >> 4) * 8;
  f32x4 acc[2][4] = {};
  const ushort* A0 = Xb + (size_t)(row0 + lr) * 256 + kg;
  const ushort* A1 = A0 + 16 * 256;
  const ushort* Bb = Wt + (size_t)(col0 + lr) * 256 + kg;
#pragma unroll
  for (int k0 = 0; k0 < 256; k0 += 32) {
    short8 a0 = *reinterpret_cast<const short8*>(A0 + k0);
    short8 a1 = *reinterpret_cast<const short8*>(A1 + k0);
#pragma unroll
    for (int fc = 0; fc < 4; ++fc) {
      short8 bf = *reinterpret_cast<const short8*>(Bb + (size_t)fc * 16 * 256 + k0);
      acc[0][fc] = __builtin_amdgcn_mfma_f32_16x16x32_bf16(a0, bf, acc[0][fc], 0, 0, 0);
      acc[1][fc] = __builtin_amdgcn_mfma_f32_16x16x32_bf16(a1, bf, acc[1][fc], 0, 0, 0);
    }
  }
  int orow = (lane >> 4) * 4;
#pragma unroll
  for (int fr = 0; fr < 2; ++fr)
#pragma unroll
    for (int fc = 0; fc < 4; ++fc)
#pragma unroll
      for (int r = 0; r < 4; ++r) {
        int row = row0 + fr * 16 + orow + r;
        int col = col0 + fc * 16 + lr;
        QKVb[(size_t)row * 768 + col] = f2b(acc[fr][fc][r]);
      }
}

// ---------------- CSR build ----------------
__global__ void hist_kernel(const int* __restrict__ src, int* __restrict__ counts, int E) {
  int e = blockIdx.x * blockDim.x + threadIdx.x;
  if (e < E) atomicAdd(&counts[src[e]], 1);
}

__global__ __launch_bounds__(1024) void scan_kernel(
    const int* __restrict__ counts, int* __restrict__ offs, int* __restrict__ cursor, int N) {
  __shared__ int wexc[16];
  __shared__ int s_total;
  __shared__ int carry_s;
  int t = threadIdx.x;
  int lane = t & 63, wv = t >> 6;
  __shared__ int wsum[16];
  if (t == 0) carry_s = 0;
  __syncthreads();
  for (int base = 0; base < N; base += 1024) {
    int i = base + t;
    int v = (i < N) ? counts[i] : 0;
    int x = v;
#pragma unroll
    for (int off = 1; off < 64; off <<= 1) {
      int y = __shfl_up(x, off);
      if (lane >= off) x += y;
    }
    if (lane == 63) wsum[wv] = x;
    __syncthreads();
    if (t < 64) {
      int s = (lane < 16) ? wsum[lane] : 0;
      int xs = s;
#pragma unroll
      for (int off = 1; off < 16; off <<= 1) {
        int y = __shfl_up(xs, off);
        if (lane >= off) xs += y;
      }
      if (lane < 16) wexc[lane] = xs - s;
      if (lane == 15) s_total = xs;
    }
    __syncthreads();
    int carry = carry_s;
    int excl = carry + wexc[wv] + (x - v);
    if (i < N) { offs[i] = excl; cursor[i] = excl; }
    __syncthreads();
    if (t == 0) carry_s += s_total;
    __syncthreads();
  }
  if (t == 0) offs[N] = carry_s;
}

__global__ void scatter_kernel(const int* __restrict__ src, const int* __restrict__ tgt,
                               const float* __restrict__ ew, int* __restrict__ cursor,
                               int* __restrict__ tgt_s, float* __restrict__ w_s, int E) {
  int e = blockIdx.x * blockDim.x + threadIdx.x;
  if (e < E) {
    int pos = atomicAdd(&cursor[src[e]], 1);
    tgt_s[pos] = tgt[e];
    w_s[pos] = ew[e];
  }
}

// ---------------- per-node attention: one WAVE per node, pipelined gathers ----
// grid ceil(N/4) x 256 threads (4 waves). Wave w owns node blockIdx.x*4+w.
// Score phase: lane (e8=l>>3, h=l&7) -> full 32-dim head dot in registers,
//   depth-2 software pipeline over 8-edge sections, padded unconditional loads.
// PV phase: lane owns dims l*4..l*4+3 (head l>>3), 8-edge load batches.
__global__ __launch_bounds__(256) void attn_kernel(
    const ushort* __restrict__ QKVb,
    const int* __restrict__ offs, const int* __restrict__ tgt_s, const float* __restrict__ w_s,
    const float* __restrict__ We, ushort* __restrict__ AGGb, int N) {
  __shared__ float s_p[4][CH][8];
  __shared__ int s_tgt[4][CH];
  __shared__ float s_w[4][CH];
  int t = threadIdx.x;
  int w = t >> 6;
  int l = t & 63;
  int i = blockIdx.x * 4 + w;
  if (i >= N) return;
  int e8 = l >> 3;
  int h = l & 7;
  int hacc = l >> 3;  // head for PV phase
  const float scale = 0.17677669529663687f;  // 1/sqrt(32)
  float we = We[h];

  // hoisted q fragment (dims h*32..h*32+31) as f32
  float qf[32];
  {
    const short8* qr = reinterpret_cast<const short8*>(QKVb + (size_t)i * 768 + h * 32);
#pragma unroll
    for (int d = 0; d < 4; ++d) {
      short8 qv = qr[d];
#pragma unroll
      for (int x = 0; x < 8; ++x) qf[d * 8 + x] = b2f((ushort)qv[x]);
    }
  }

  float m = -1e30f, lsum = 0.f;
  float acc0 = 0.f, acc1 = 0.f, acc2 = 0.f, acc3 = 0.f;
  int beg = offs[i], end = offs[i + 1];

  for (int base = beg; base < end; base += CH) {
    int cnt = min(CH, end - base);
    int cnt_pad = (cnt + 7) & ~7;
    // stage edge list, padded with self-node (valid address, p will be 0)
    {
      bool valid = l < cnt;
      int tg = valid ? tgt_s[base + l] : i;
      float ww = valid ? w_s[base + l] : 0.f;
      s_tgt[w][l] = tg;
      s_w[w][l] = ww;
    }
    wave_lds_sync();

    // ---- score phase: depth-2 pipelined sections of 8 edges ----
    float s_local[8];
#pragma unroll
    for (int it = 0; it < 8; ++it) s_local[it] = -1e30f;

    short8 kc[4], kn[4];
    {
      const short8* p = reinterpret_cast<const short8*>(
          QKVb + (size_t)s_tgt[w][e8] * 768 + 256 + h * 32);
#pragma unroll
      for (int d = 0; d < 4; ++d) kc[d] = p[d];
    }
    if (8 < cnt_pad) {
      const short8* p = reinterpret_cast<const short8*>(
          QKVb + (size_t)s_tgt[w][8 + e8] * 768 + 256 + h * 32);
#pragma unroll
      for (int d = 0; d < 4; ++d) kn[d] = p[d];
    }
    float cmax = -1e30f;
#pragma unroll
    for (int it = 0; it < 8; ++it) {
      if (it * 8 >= cnt_pad) break;  // wave-uniform
      float dot = 0.f;
#pragma unroll
      for (int d = 0; d < 4; ++d)
#pragma unroll
        for (int x = 0; x < 8; ++x)
          dot += qf[d * 8 + x] * b2f((ushort)kc[d][x]);
      int j = it * 8 + e8;
      float s = (j < cnt) ? dot * scale + s_w[w][j] * we : -1e30f;
      s_local[it] = s;
      cmax = fmaxf(cmax, s);
      // rotate pipeline
#pragma unroll
      for (int d = 0; d < 4; ++d) kc[d] = kn[d];
      if ((it + 2) * 8 < cnt_pad) {
        const short8* p = reinterpret_cast<const short8*>(
            QKVb + (size_t)s_tgt[w][(it + 2) * 8 + e8] * 768 + 256 + h * 32);
#pragma unroll
        for (int d = 0; d < 4; ++d) kn[d] = p[d];
      }
    }
    // per-head reduce over e8 lanes (stride-8 groups)
    cmax = fmaxf(cmax, __shfl_xor(cmax, 8));
    cmax = fmaxf(cmax, __shfl_xor(cmax, 16));
    cmax = fmaxf(cmax, __shfl_xor(cmax, 32));
    float newm = fmaxf(m, cmax);
    float f = __expf(m - newm);
    float psum = 0.f;
#pragma unroll
    for (int it = 0; it < 8; ++it) {
      if (it * 8 >= cnt_pad) break;  // wave-uniform
      int j = it * 8 + e8;
      float p = __expf(s_local[it] - newm);  // pads: exp(-1e30-.) = 0
      s_p[w][j][h] = p;
      psum += p;
    }
    psum += __shfl_xor(psum, 8);
    psum += __shfl_xor(psum, 16);
    psum += __shfl_xor(psum, 32);
    lsum = lsum * f + psum;
    m = newm;
    float f_acc = __shfl(f, hacc);
    acc0 *= f_acc; acc1 *= f_acc; acc2 *= f_acc; acc3 *= f_acc;
    wave_lds_sync();

    // ---- PV phase: 8-edge load batches ----
#pragma unroll
    for (int g = 0; g < 8; ++g) {
      if (g * 8 >= cnt_pad) break;  // wave-uniform
      float pv[8];
      short4_t vv[8];
#pragma unroll
      for (int k = 0; k < 8; ++k) {
        int j = g * 8 + k;
        pv[k] = s_p[w][j][hacc];
        vv[k] = *reinterpret_cast<const short4_t*>(
            QKVb + (size_t)s_tgt[w][j] * 768 + 512 + l * 4);
      }
#pragma unroll
      for (int k = 0; k < 8; ++k) {
        acc0 += pv[k] * b2f((ushort)vv[k][0]);
        acc1 += pv[k] * b2f((ushort)vv[k][1]);
        acc2 += pv[k] * b2f((ushort)vv[k][2]);
        acc3 += pv[k] * b2f((ushort)vv[k][3]);
      }
    }
    wave_lds_sync();  // before next chunk overwrites staging
  }
  float lsum_acc = __shfl(lsum, hacc);
  float rinv = (lsum_acc > 0.f) ? 1.f / lsum_acc : 0.f;
  short4_t o;
  o[0] = (short)f2b(acc0 * rinv);
  o[1] = (short)f2b(acc1 * rinv);
  o[2] = (short)f2b(acc2 * rinv);
  o[3] = (short)f2b(acc3 * rinv);
  *reinterpret_cast<short4_t*>(AGGb + (size_t)i * 256 + l * 4) = o;
}

// ---------------- output MFMA GEMM + residual + LayerNorm ----------------
__global__ __launch_bounds__(256) void out_mfma(
    const ushort* __restrict__ AGGb, const ushort* __restrict__ Wot,
    const float* __restrict__ X, const float* __restrict__ g, const float* __restrict__ bb,
    float* __restrict__ out, int N) {
  __shared__ float S[32][264];
  __shared__ float s_mu[32], s_rs[32];
  int t = threadIdx.x;
  int lane = t & 63, wid = t >> 6;
  int row0 = blockIdx.x * 32;
  int col0 = wid * 64;
  int lr = lane & 15, kg = (lane >> 4) * 8;
  f32x4 acc[2][4] = {};
  const ushort* A0 = AGGb + (size_t)(row0 + lr) * 256 + kg;
  const ushort* A1 = A0 + 16 * 256;
  const ushort* Bb = Wot + (size_t)(col0 + lr) * 256 + kg;
#pragma unroll
  for (int k0 = 0; k0 < 256; k0 += 32) {
    short8 a0 = *reinterpret_cast<const short8*>(A0 + k0);
    short8 a1 = *reinterpret_cast<const short8*>(A1 + k0);
#pragma unroll
    for (int fc = 0; fc < 4; ++fc) {
      short8 bf = *reinterpret_cast<const short8*>(Bb + (size_t)fc * 16 * 256 + k0);
      acc[0][fc] = __builtin_amdgcn_mfma_f32_16x16x32_bf16(a0, bf, acc[0][fc], 0, 0, 0);
      acc[1][fc] = __builtin_amdgcn_mfma_f32_16x16x32_bf16(a1, bf, acc[1][fc], 0, 0, 0);
    }
  }
  int orow = (lane >> 4) * 4;
#pragma unroll
  for (int fr = 0; fr < 2; ++fr)
#pragma unroll
    for (int fc = 0; fc < 4; ++fc)
#pragma unroll
      for (int r = 0; r < 4; ++r) {
        int row = fr * 16 + orow + r;
        int col = col0 + fc * 16 + lr;
        S[row][col] = acc[fr][fc][r] + X[(size_t)(row0 + row) * 256 + col];
      }
  __syncthreads();
  for (int r = wid; r < 32; r += 4) {
    float s = 0.f, ss = 0.f;
    for (int c = lane; c < 256; c += 64) {
      float v = S[r][c];
      s += v;
      ss += v * v;
    }
#pragma unroll
    for (int off = 32; off; off >>= 1) {
      s += __shfl_xor(s, off);
      ss += __shfl_xor(ss, off);
    }
    if (lane == 0) {
      float mu = s * (1.f / 256.f);
      float var = ss * (1.f / 256.f) - mu * mu;
      s_mu[r] = mu;
      s_rs[r] = rsqrtf(var + 1e-5f);
    }
  }
  __syncthreads();
  float gg = g[t], bbv = bb[t];
  for (int r = 0; r < 32; ++r) {
    out[(size_t)(row0 + r) * 256 + t] = (S[r][t] - s_mu[r]) * s_rs[r] * gg + bbv;
  }
}

extern "C" void kernel_launch(void* const* d_in, const int* in_sizes, int n_in,
                              void* d_out, int out_size, void* d_ws, size_t ws_size,
                              hipStream_t stream) {
  const float* X  = (const float*)d_in[0];
  const int* eidx = (const int*)d_in[1];
  const float* ew = (const float*)d_in[2];
  const float* Wq = (const float*)d_in[3];
  const float* Wk = (const float*)d_in[4];
  const float* Wv = (const float*)d_in[5];
  const float* We = (const float*)d_in[6];
  const float* Wo = (const float*)d_in[7];
  const float* g  = (const float*)d_in[8];
  const float* b  = (const float*)d_in[9];
  int N = in_sizes[0] / 256;
  int E = in_sizes[1] / 2;
  const int* src = eidx;
  const int* tgt = eidx + E;
  float* out = (float*)d_out;

  char* w = (char*)d_ws;
  ushort* Xb   = (ushort*)w;  w += (size_t)N * 256 * 2;
  ushort* Wt   = (ushort*)w;  w += (size_t)1024 * 256 * 2;
  ushort* QKVb = (ushort*)w;  w += (size_t)N * 768 * 2;
  ushort* AGGb = (ushort*)w;  w += (size_t)N * 256 * 2;
  int* counts  = (int*)w;     w += (size_t)N * 4;
  int* offs    = (int*)w;     w += (size_t)(N + 1) * 4;
  int* cursor  = (int*)w;     w += (size_t)N * 4;
  int* tgt_s   = (int*)w;     w += (size_t)E * 4;
  float* w_s   = (float*)w;   w += (size_t)E * 4;
  const ushort* Wot = Wt + (size_t)768 * 256;

  hipMemsetAsync(counts, 0, (size_t)N * 4, stream);
  convert_x<<<(N * 256 + 2047) / 2048, 256, 0, stream>>>(X, Xb, N * 256);
  convert_w<<<256, 256, 0, stream>>>(Wq, Wk, Wv, Wo, Wt);
  gemm_qkv<<<dim3(N / 32, 3), 256, 0, stream>>>(Xb, Wt, QKVb, N);
  hist_kernel<<<(E + 255) / 256, 256, 0, stream>>>(src, counts, E);
  scan_kernel<<<1, 1024, 0, stream>>>(counts, offs, cursor, N);
  scatter_kernel<<<(E + 255) / 256, 256, 0, stream>>>(src, tgt, ew, cursor, tgt_s, w_s, E);
  attn_kernel<<<(N + 3) / 4, 256, 0, stream>>>(QKVb, offs, tgt_s, w_s, We, AGGb, N);
  out_mfma<<<N / 32, 256, 0, stream>>>(AGGb, Wot, X, g, b, out, N);
}

// Round 5
// 143.741 us; speedup vs baseline: 4.4845x; 1.3739x over previous
//
#include <hip/hip_runtime.h>
#include <hip/hip_bf16.h>

typedef __attribute__((ext_vector_type(8))) short short8;
typedef __attribute__((ext_vector_type(4))) short short4_t;
typedef __attribute__((ext_vector_type(4))) float f32x4;

#define CH 64

__device__ __forceinline__ ushort f2b(float f) {
  __hip_bfloat16 h = __float2bfloat16(f);
  return *reinterpret_cast<ushort*>(&h);
}
__device__ __forceinline__ float b2f(ushort u) {
  return __uint_as_float(((unsigned)u) << 16);
}
__device__ __forceinline__ void wave_lds_sync() {
  asm volatile("s_waitcnt lgkmcnt(0)" ::: "memory");
  __builtin_amdgcn_wave_barrier();
}

// ---------------- fused pre: convert X, convert+transpose W, zero counts ----
// blocks [0,nxb): convert_x; [nxb,nxb+256): convert_w; rest: zero counts
__global__ __launch_bounds__(256) void pre_kernel(
    const float* __restrict__ X, ushort* __restrict__ Xb, int nX,
    const float* __restrict__ Wq, const float* __restrict__ Wk,
    const float* __restrict__ Wv, const float* __restrict__ Wo,
    ushort* __restrict__ Wt, int* __restrict__ counts, int N, int nxb) {
  __shared__ float L[32][33];
  int b = blockIdx.x;
  int t = threadIdx.x;
  if (b < nxb) {
    int i = (b * 256 + t) * 8;
    if (i >= nX) return;
    float4 x0 = *reinterpret_cast<const float4*>(X + i);
    float4 x1 = *reinterpret_cast<const float4*>(X + i + 4);
    short8 o;
    o[0] = (short)f2b(x0.x); o[1] = (short)f2b(x0.y);
    o[2] = (short)f2b(x0.z); o[3] = (short)f2b(x0.w);
    o[4] = (short)f2b(x1.x); o[5] = (short)f2b(x1.y);
    o[6] = (short)f2b(x1.z); o[7] = (short)f2b(x1.w);
    *reinterpret_cast<short8*>(Xb + i) = o;
  } else if (b < nxb + 256) {
    int bx = b - nxb;
    int mat = bx >> 6;
    int tile = bx & 63;
    int tr = (tile >> 3) * 32;
    int tc = (tile & 7) * 32;
    const float* W = (mat == 0) ? Wq : (mat == 1) ? Wk : (mat == 2) ? Wv : Wo;
    int c = t & 31, r8 = t >> 5;
#pragma unroll
    for (int rr = 0; rr < 4; ++rr) {
      int r = r8 + rr * 8;
      L[r][c] = W[(size_t)(tr + r) * 256 + tc + c];
    }
    __syncthreads();
#pragma unroll
    for (int rr = 0; rr < 4; ++rr) {
      int cc = r8 + rr * 8;
      Wt[(size_t)(mat * 256 + tc + cc) * 256 + tr + c] = f2b(L[c][cc]);
    }
  } else {
    int i = (b - nxb - 256) * 256 + t;
    if (i < N) counts[i] = 0;
  }
}

// ---------------- fused: QKV MFMA GEMM (LDS-staged, swizzled) + hist --------
// blocks [0,ngemm): gemm tile (bx=bid/6 rows, by=bid%6 col-tile of 768)
// blocks [ngemm,..): histogram of src
__global__ __launch_bounds__(256) void hist_gemm(
    const ushort* __restrict__ Xb, const ushort* __restrict__ Wt,
    ushort* __restrict__ QKVb, const int* __restrict__ src,
    int* __restrict__ counts, int N, int E, int ngemm) {
  __shared__ ushort sA[128 * 64];
  __shared__ ushort sB[128 * 64];
  int bid = blockIdx.x;
  int t = threadIdx.x;
  if (bid >= ngemm) {
    int e = (bid - ngemm) * 256 + t;
    if (e < E) atomicAdd(&counts[src[e]], 1);
    return;
  }
  int bx = bid / 6, by = bid % 6;
  char* cA = (char*)sA;
  char* cB = (char*)sB;
  int lane = t & 63, w = t >> 6;
  int wr = w >> 1, wc = w & 1;
  int row0 = bx * 128;
  int lr = lane & 15, kg = lane >> 4;
  f32x4 acc[4][4] = {};
  for (int k0 = 0; k0 < 256; k0 += 64) {
#pragma unroll
    for (int it = 0; it < 4; ++it) {
      int slot = t + it * 256;
      int row = slot >> 3, kc = slot & 7;
      int grow = min(row0 + row, N - 1);
      short8 va = *reinterpret_cast<const short8*>(Xb + (size_t)grow * 256 + k0 + kc * 8);
      *reinterpret_cast<short8*>(cA + ((row * 128 + kc * 16) ^ ((row & 7) << 4))) = va;
      short8 vb = *reinterpret_cast<const short8*>(Wt + (size_t)(by * 128 + row) * 256 + k0 + kc * 8);
      *reinterpret_cast<short8*>(cB + ((row * 128 + kc * 16) ^ ((row & 7) << 4))) = vb;
    }
    __syncthreads();
#pragma unroll
    for (int ks = 0; ks < 2; ++ks) {
      short8 af[4], bf[4];
#pragma unroll
      for (int fr = 0; fr < 4; ++fr) {
        int row = wr * 64 + fr * 16 + lr;
        af[fr] = *reinterpret_cast<const short8*>(
            cA + ((row * 128 + ks * 64 + kg * 16) ^ ((row & 7) << 4)));
      }
#pragma unroll
      for (int fc = 0; fc < 4; ++fc) {
        int col = wc * 64 + fc * 16 + lr;
        bf[fc] = *reinterpret_cast<const short8*>(
            cB + ((col * 128 + ks * 64 + kg * 16) ^ ((col & 7) << 4)));
      }
#pragma unroll
      for (int fr = 0; fr < 4; ++fr)
#pragma unroll
        for (int fc = 0; fc < 4; ++fc)
          acc[fr][fc] = __builtin_amdgcn_mfma_f32_16x16x32_bf16(af[fr], bf[fc], acc[fr][fc], 0, 0, 0);
    }
    __syncthreads();
  }
  int orow = kg * 4;
#pragma unroll
  for (int fr = 0; fr < 4; ++fr)
#pragma unroll
    for (int fc = 0; fc < 4; ++fc)
#pragma unroll
      for (int r = 0; r < 4; ++r) {
        int row = row0 + wr * 64 + fr * 16 + orow + r;
        int col = by * 128 + wc * 64 + fc * 16 + lr;
        if (row < N) QKVb[(size_t)row * 768 + col] = f2b(acc[fr][fc][r]);
      }
}

// ---------------- scan ----------------
__global__ __launch_bounds__(1024) void scan_kernel(
    const int* __restrict__ counts, int* __restrict__ offs, int* __restrict__ cursor, int N) {
  __shared__ int wexc[16];
  __shared__ int s_total;
  __shared__ int carry_s;
  int t = threadIdx.x;
  int lane = t & 63, wv = t >> 6;
  __shared__ int wsum[16];
  if (t == 0) carry_s = 0;
  __syncthreads();
  for (int base = 0; base < N; base += 1024) {
    int i = base + t;
    int v = (i < N) ? counts[i] : 0;
    int x = v;
#pragma unroll
    for (int off = 1; off < 64; off <<= 1) {
      int y = __shfl_up(x, off);
      if (lane >= off) x += y;
    }
    if (lane == 63) wsum[wv] = x;
    __syncthreads();
    if (t < 64) {
      int s = (lane < 16) ? wsum[lane] : 0;
      int xs = s;
#pragma unroll
      for (int off = 1; off < 16; off <<= 1) {
        int y = __shfl_up(xs, off);
        if (lane >= off) xs += y;
      }
      if (lane < 16) wexc[lane] = xs - s;
      if (lane == 15) s_total = xs;
    }
    __syncthreads();
    int carry = carry_s;
    int excl = carry + wexc[wv] + (x - v);
    if (i < N) { offs[i] = excl; cursor[i] = excl; }
    __syncthreads();
    if (t == 0) carry_s += s_total;
    __syncthreads();
  }
  if (t == 0) offs[N] = carry_s;
}

__global__ void scatter_kernel(const int* __restrict__ src, const int* __restrict__ tgt,
                               const float* __restrict__ ew, int* __restrict__ cursor,
                               int* __restrict__ tgt_s, float* __restrict__ w_s, int E) {
  int e = blockIdx.x * blockDim.x + threadIdx.x;
  if (e < E) {
    int pos = atomicAdd(&cursor[src[e]], 1);
    tgt_s[pos] = tgt[e];
    w_s[pos] = ew[e];
  }
}

// ---------------- per-node attention: one WAVE per node, pipelined gathers ----
__global__ __launch_bounds__(256) void attn_kernel(
    const ushort* __restrict__ QKVb,
    const int* __restrict__ offs, const int* __restrict__ tgt_s, const float* __restrict__ w_s,
    const float* __restrict__ We, ushort* __restrict__ AGGb, int N) {
  __shared__ float s_p[4][CH][8];
  __shared__ int s_tgt[4][CH];
  __shared__ float s_w[4][CH];
  int t = threadIdx.x;
  int w = t >> 6;
  int l = t & 63;
  int i = blockIdx.x * 4 + w;
  if (i >= N) return;
  int e8 = l >> 3;
  int h = l & 7;
  int hacc = l >> 3;
  const float scale = 0.17677669529663687f;
  float we = We[h];

  float qf[32];
  {
    const short8* qr = reinterpret_cast<const short8*>(QKVb + (size_t)i * 768 + h * 32);
#pragma unroll
    for (int d = 0; d < 4; ++d) {
      short8 qv = qr[d];
#pragma unroll
      for (int x = 0; x < 8; ++x) qf[d * 8 + x] = b2f((ushort)qv[x]);
    }
  }

  float m = -1e30f, lsum = 0.f;
  float acc0 = 0.f, acc1 = 0.f, acc2 = 0.f, acc3 = 0.f;
  int beg = offs[i], end = offs[i + 1];

  for (int base = beg; base < end; base += CH) {
    int cnt = min(CH, end - base);
    int cnt_pad = (cnt + 7) & ~7;
    {
      bool valid = l < cnt;
      int tg = valid ? tgt_s[base + l] : i;
      float ww = valid ? w_s[base + l] : 0.f;
      s_tgt[w][l] = tg;
      s_w[w][l] = ww;
    }
    wave_lds_sync();

    float s_local[8];
#pragma unroll
    for (int it = 0; it < 8; ++it) s_local[it] = -1e30f;

    short8 kc[4], kn[4];
    {
      const short8* p = reinterpret_cast<const short8*>(
          QKVb + (size_t)s_tgt[w][e8] * 768 + 256 + h * 32);
#pragma unroll
      for (int d = 0; d < 4; ++d) kc[d] = p[d];
    }
    if (8 < cnt_pad) {
      const short8* p = reinterpret_cast<const short8*>(
          QKVb + (size_t)s_tgt[w][8 + e8] * 768 + 256 + h * 32);
#pragma unroll
      for (int d = 0; d < 4; ++d) kn[d] = p[d];
    }
    float cmax = -1e30f;
#pragma unroll
    for (int it = 0; it < 8; ++it) {
      if (it * 8 >= cnt_pad) break;
      float dot = 0.f;
#pragma unroll
      for (int d = 0; d < 4; ++d)
#pragma unroll
        for (int x = 0; x < 8; ++x)
          dot += qf[d * 8 + x] * b2f((ushort)kc[d][x]);
      int j = it * 8 + e8;
      float s = (j < cnt) ? dot * scale + s_w[w][j] * we : -1e30f;
      s_local[it] = s;
      cmax = fmaxf(cmax, s);
#pragma unroll
      for (int d = 0; d < 4; ++d) kc[d] = kn[d];
      if ((it + 2) * 8 < cnt_pad) {
        const short8* p = reinterpret_cast<const short8*>(
            QKVb + (size_t)s_tgt[w][(it + 2) * 8 + e8] * 768 + 256 + h * 32);
#pragma unroll
        for (int d = 0; d < 4; ++d) kn[d] = p[d];
      }
    }
    cmax = fmaxf(cmax, __shfl_xor(cmax, 8));
    cmax = fmaxf(cmax, __shfl_xor(cmax, 16));
    cmax = fmaxf(cmax, __shfl_xor(cmax, 32));
    float newm = fmaxf(m, cmax);
    float f = __expf(m - newm);
    float psum = 0.f;
#pragma unroll
    for (int it = 0; it < 8; ++it) {
      if (it * 8 >= cnt_pad) break;
      int j = it * 8 + e8;
      float p = __expf(s_local[it] - newm);
      s_p[w][j][h] = p;
      psum += p;
    }
    psum += __shfl_xor(psum, 8);
    psum += __shfl_xor(psum, 16);
    psum += __shfl_xor(psum, 32);
    lsum = lsum * f + psum;
    m = newm;
    float f_acc = __shfl(f, hacc);
    acc0 *= f_acc; acc1 *= f_acc; acc2 *= f_acc; acc3 *= f_acc;
    wave_lds_sync();

#pragma unroll
    for (int g = 0; g < 8; ++g) {
      if (g * 8 >= cnt_pad) break;
      float pv[8];
      short4_t vv[8];
#pragma unroll
      for (int k = 0; k < 8; ++k) {
        int j = g * 8 + k;
        pv[k] = s_p[w][j][hacc];
        vv[k] = *reinterpret_cast<const short4_t*>(
            QKVb + (size_t)s_tgt[w][j] * 768 + 512 + l * 4);
      }
#pragma unroll
      for (int k = 0; k < 8; ++k) {
        acc0 += pv[k] * b2f((ushort)vv[k][0]);
        acc1 += pv[k] * b2f((ushort)vv[k][1]);
        acc2 += pv[k] * b2f((ushort)vv[k][2]);
        acc3 += pv[k] * b2f((ushort)vv[k][3]);
      }
    }
    wave_lds_sync();
  }
  float lsum_acc = __shfl(lsum, hacc);
  float rinv = (lsum_acc > 0.f) ? 1.f / lsum_acc : 0.f;
  short4_t o;
  o[0] = (short)f2b(acc0 * rinv);
  o[1] = (short)f2b(acc1 * rinv);
  o[2] = (short)f2b(acc2 * rinv);
  o[3] = (short)f2b(acc3 * rinv);
  *reinterpret_cast<short4_t*>(AGGb + (size_t)i * 256 + l * 4) = o;
}

// ------- output GEMM (LDS-staged, BM=64 BN=256) + residual + LayerNorm ------
// 4 waves; wave w owns rows row0+w*16 .. +15 (full 256-col width) -> LN wave-local.
__global__ __launch_bounds__(256) void out_ln(
    const ushort* __restrict__ AGGb, const ushort* __restrict__ Wot,
    const float* __restrict__ X, const float* __restrict__ g, const float* __restrict__ bb,
    float* __restrict__ out, int N) {
  __shared__ ushort sA[64 * 64];    // 8KB
  __shared__ ushort sB[256 * 64];   // 32KB
  char* cA = (char*)sA;
  char* cB = (char*)sB;
  int t = threadIdx.x;
  int lane = t & 63, w = t >> 6;
  int row0 = blockIdx.x * 64;
  int lr = lane & 15, kg = lane >> 4;
  f32x4 acc[16] = {};
  for (int k0 = 0; k0 < 256; k0 += 64) {
#pragma unroll
    for (int it = 0; it < 2; ++it) {
      int slot = t + it * 256;
      int row = slot >> 3, kc = slot & 7;
      int grow = min(row0 + row, N - 1);
      short8 va = *reinterpret_cast<const short8*>(AGGb + (size_t)grow * 256 + k0 + kc * 8);
      *reinterpret_cast<short8*>(cA + ((row * 128 + kc * 16) ^ ((row & 7) << 4))) = va;
    }
#pragma unroll
    for (int it = 0; it < 8; ++it) {
      int slot = t + it * 256;
      int col = slot >> 3, kc = slot & 7;
      short8 vb = *reinterpret_cast<const short8*>(Wot + (size_t)col * 256 + k0 + kc * 8);
      *reinterpret_cast<short8*>(cB + ((col * 128 + kc * 16) ^ ((col & 7) << 4))) = vb;
    }
    __syncthreads();
#pragma unroll
    for (int ks = 0; ks < 2; ++ks) {
      int arow = w * 16 + lr;
      short8 a = *reinterpret_cast<const short8*>(
          cA + ((arow * 128 + ks * 64 + kg * 16) ^ ((arow & 7) << 4)));
#pragma unroll
      for (int fc = 0; fc < 16; ++fc) {
        int col = fc * 16 + lr;
        short8 b = *reinterpret_cast<const short8*>(
            cB + ((col * 128 + ks * 64 + kg * 16) ^ ((col & 7) << 4)));
        acc[fc] = __builtin_amdgcn_mfma_f32_16x16x32_bf16(a, b, acc[fc], 0, 0, 0);
      }
    }
    __syncthreads();
  }
  // epilogue: residual + LayerNorm, wave-local rows
  float g16[16], b16[16];
#pragma unroll
  for (int fc = 0; fc < 16; ++fc) {
    g16[fc] = g[fc * 16 + lr];
    b16[fc] = bb[fc * 16 + lr];
  }
#pragma unroll
  for (int r = 0; r < 4; ++r) {
    int rowl = kg * 4 + r;
    int grow = row0 + w * 16 + rowl;
    int growc = min(grow, N - 1);
    float xv[16];
    float s = 0.f, ss = 0.f;
#pragma unroll
    for (int fc = 0; fc < 16; ++fc) {
      float v = acc[fc][r] + X[(size_t)growc * 256 + fc * 16 + lr];
      xv[fc] = v;
      s += v;
      ss += v * v;
    }
    s += __shfl_xor(s, 1);  ss += __shfl_xor(ss, 1);
    s += __shfl_xor(s, 2);  ss += __shfl_xor(ss, 2);
    s += __shfl_xor(s, 4);  ss += __shfl_xor(ss, 4);
    s += __shfl_xor(s, 8);  ss += __shfl_xor(ss, 8);
    float mu = s * (1.f / 256.f);
    float var = ss * (1.f / 256.f) - mu * mu;
    float rs = rsqrtf(var + 1e-5f);
    if (grow < N) {
#pragma unroll
      for (int fc = 0; fc < 16; ++fc)
        out[(size_t)grow * 256 + fc * 16 + lr] = (xv[fc] - mu) * rs * g16[fc] + b16[fc];
    }
  }
}

extern "C" void kernel_launch(void* const* d_in, const int* in_sizes, int n_in,
                              void* d_out, int out_size, void* d_ws, size_t ws_size,
                              hipStream_t stream) {
  const float* X  = (const float*)d_in[0];
  const int* eidx = (const int*)d_in[1];
  const float* ew = (const float*)d_in[2];
  const float* Wq = (const float*)d_in[3];
  const float* Wk = (const float*)d_in[4];
  const float* Wv = (const float*)d_in[5];
  const float* We = (const float*)d_in[6];
  const float* Wo = (const float*)d_in[7];
  const float* g  = (const float*)d_in[8];
  const float* b  = (const float*)d_in[9];
  int N = in_sizes[0] / 256;
  int E = in_sizes[1] / 2;
  const int* src = eidx;
  const int* tgt = eidx + E;
  float* out = (float*)d_out;

  char* w = (char*)d_ws;
  ushort* Xb   = (ushort*)w;  w += (size_t)N * 256 * 2;
  ushort* Wt   = (ushort*)w;  w += (size_t)1024 * 256 * 2;
  ushort* QKVb = (ushort*)w;  w += (size_t)N * 768 * 2;
  ushort* AGGb = (ushort*)w;  w += (size_t)N * 256 * 2;
  int* counts  = (int*)w;     w += (size_t)N * 4;
  int* offs    = (int*)w;     w += (size_t)(N + 1) * 4;
  int* cursor  = (int*)w;     w += (size_t)N * 4;
  int* tgt_s   = (int*)w;     w += (size_t)E * 4;
  float* w_s   = (float*)w;   w += (size_t)E * 4;
  const ushort* Wot = Wt + (size_t)768 * 256;

  int nX = N * 256;
  int nxb = (nX / 8 + 255) / 256;
  int nzero = (N + 255) / 256;
  pre_kernel<<<nxb + 256 + nzero, 256, 0, stream>>>(X, Xb, nX, Wq, Wk, Wv, Wo, Wt, counts, N, nxb);

  int ngemm = ((N + 127) / 128) * 6;
  int nhist = (E + 255) / 256;
  hist_gemm<<<ngemm + nhist, 256, 0, stream>>>(Xb, Wt, QKVb, src, counts, N, E, ngemm);

  scan_kernel<<<1, 1024, 0, stream>>>(counts, offs, cursor, N);
  scatter_kernel<<<(E + 255) / 256, 256, 0, stream>>>(src, tgt, ew, cursor, tgt_s, w_s, E);
  attn_kernel<<<(N + 3) / 4, 256, 0, stream>>>(QKVb, offs, tgt_s, w_s, We, AGGb, N);
  out_ln<<<(N + 63) / 64, 256, 0, stream>>>(AGGb, Wot, X, g, b, out, N);
}